// Round 1
// baseline (499.912 us; speedup 1.0000x reference)
//
#include <hip/hip_runtime.h>
#include <hip/hip_bf16.h>

// Problem constants
constexpr int kB   = 2;
constexpr int kH   = 8;
constexpr int kG   = 4;
constexpr int kS   = 14;
constexpr int kSS  = 196;   // S*S
constexpr int kKey = 784;   // G*S*S keys per (b,h)
constexpr int kMid = 96;
constexpr int kQR  = 28;    // 4 g * 7 j query rows per attention block
constexpr float kScl = 0.10206207261596577f; // 1/sqrt(96)

// ---------------- workspace layout (float elements) ----------------
constexpr size_t SZ_QKV = (size_t)kB*kH*kG*kSS*kMid;   // 1,204,224
constexpr size_t OFF_Q  = 0;
constexpr size_t OFF_K  = OFF_Q + SZ_QKV;
constexpr size_t OFF_V  = OFF_K + SZ_QKV;
constexpr size_t OFF_FR = OFF_V + SZ_QKV;              // 27*32 row table
constexpr size_t OFF_FC = OFF_FR + 27*32;              // 27*32 col table
constexpr size_t OFF_PS = OFF_FC + 27*32;              // Psum
constexpr size_t SZ_PS  = (size_t)kB*kH*kG*kSS*kKey;   // 9,834,496
constexpr size_t OFF_VO = OFF_PS + SZ_PS;              // vo: 1,204,224
// total = 14,653,120 floats = 58.6 MB

// ============================================================
// Kernel 1: embed tables. row_rel/col_rel only take values n/13, n in [-13,13],
// so the whole (G,S,S,S,S,32) embed tensors reduce to two 27x32 tables.
// ============================================================
__global__ void k_tables(const float* __restrict__ rw1, const float* __restrict__ rb1,
                         const float* __restrict__ rgam, const float* __restrict__ rbet,
                         const float* __restrict__ rw2, const float* __restrict__ rb2,
                         const float* __restrict__ cw1, const float* __restrict__ cb1,
                         const float* __restrict__ cgam, const float* __restrict__ cbet,
                         const float* __restrict__ cw2, const float* __restrict__ cb2,
                         float* __restrict__ frow, float* __restrict__ fcol) {
  int t = threadIdx.x;
  if (t >= 54) return;
  int which = t / 27;
  int n = t % 27;
  float tv = (float)(n - 13) / 13.0f;
  const float* w1  = which ? cw1  : rw1;
  const float* b1  = which ? cb1  : rb1;
  const float* gam = which ? cgam : rgam;
  const float* bet = which ? cbet : rbet;
  const float* w2  = which ? cw2  : rw2;
  const float* b2  = which ? cb2  : rb2;
  float h[16];
  float mu = 0.f;
#pragma unroll
  for (int d = 0; d < 16; ++d) { h[d] = tv * w1[d] + b1[d]; mu += h[d]; }
  mu *= (1.0f/16.0f);
  float var = 0.f;
#pragma unroll
  for (int d = 0; d < 16; ++d) { float z = h[d] - mu; var += z*z; }
  var *= (1.0f/16.0f);
  float rstd = rsqrtf(var + 1e-5f);
#pragma unroll
  for (int d = 0; d < 16; ++d) {
    float z = (h[d] - mu) * rstd * gam[d] + bet[d];
    h[d] = z / (1.0f + expf(-z));   // silu
  }
  float* outp = (which ? fcol : frow) + n*32;
  for (int c = 0; c < 32; ++c) {
    float o = b2[c];
#pragma unroll
    for (int d = 0; d < 16; ++d) o += h[d] * w2[d*32 + c];
    outp[c] = o;
  }
}

// ============================================================
// Kernel 2: QKV projection. Output layout [b][h][g][ij][c] (c=MID contiguous),
// with d = c*8 + h per the reference reshape(MID, HEADS).
// grid (112, 3): x = (b,g,i), y = tensor
// ============================================================
__global__ __launch_bounds__(256)
void k_qkv(const float* __restrict__ x,
           const float* __restrict__ Wq, const float* __restrict__ bq,
           const float* __restrict__ Wk, const float* __restrict__ bk,
           const float* __restrict__ Wv, const float* __restrict__ bv,
           float* __restrict__ Q, float* __restrict__ K, float* __restrict__ V) {
  const int bid = blockIdx.x;
  const int ten = blockIdx.y;
  const int i = bid % 14;
  const int g = (bid / 14) % 4;
  const int b = bid / 56;
  const float* W    = (ten == 0) ? Wq : (ten == 1) ? Wk : Wv;
  const float* bias = (ten == 0) ? bq : (ten == 1) ? bk : bv;
  float* O          = (ten == 0) ? Q  : (ten == 1) ? K  : V;

  __shared__ float xs[96][14];
  for (int idx = threadIdx.x; idx < 96*14; idx += 256) {
    int cin = idx / 14, j = idx % 14;
    xs[cin][j] = x[((size_t)(b*96 + cin)*4 + g)*196 + i*14 + j];
  }
  __syncthreads();

  for (int d = threadIdx.x; d < 768; d += 256) {
    int c = d >> 3, h = d & 7;
    float bvv = bias[d];
    float acc[14];
#pragma unroll
    for (int j = 0; j < 14; ++j) acc[j] = bvv;
    const float* wrow = W + (size_t)d * 96;
    for (int cc = 0; cc < 96; cc += 4) {
      float4 w = *(const float4*)(wrow + cc);
#pragma unroll
      for (int j = 0; j < 14; ++j)
        acc[j] += w.x*xs[cc][j] + w.y*xs[cc+1][j] + w.z*xs[cc+2][j] + w.w*xs[cc+3][j];
    }
    float* op = O + ((size_t)((b*8 + h)*4 + g)*196 + i*14)*96 + c;
#pragma unroll
    for (int j = 0; j < 14; ++j) op[(size_t)j*96] = acc[j];
  }
}

// ============================================================
// Kernel 3: fused content-logits + positional/group bias + softmax.
// Block = (b, h, i, jhalf): 28 query rows (4 g x 7 j) vs all 784 keys.
// Writes Psum[b][h][v][ij][fk] = sum_g softmax_probs  (g-sum folded in, so PV
// is a clean GEMM afterwards).
// ============================================================
__global__ __launch_bounds__(256, 2)
void k_attn(const float* __restrict__ Q, const float* __restrict__ K,
            const float* __restrict__ frow_g, const float* __restrict__ fcol_g,
            const float* __restrict__ gemb_g, float* __restrict__ Psum) {
  const int tid = threadIdx.x;
  const int bid = blockIdx.x;
  const int jhalf = bid & 1;
  const int t2 = bid >> 1;
  const int qi = t2 % 14;
  const int hh = (t2 / 14) % 8;
  const int bb = t2 / 112;
  const int bh = bb*8 + hh;

  __shared__ float qs[kQR][96];
  __shared__ float frow[27][32];
  __shared__ float fcol[27][32];
  __shared__ float gembs[4][32];
  __shared__ float Arr[kQR][27];
  __shared__ float Acl[kQR][27];
  __shared__ float Agg[kQR][4];
  __shared__ __hip_bfloat16 contl[kQR][kKey];   // content logits, bf16 (44 KB)
  __shared__ float redw[kQR][4];
  __shared__ float Ms[kQR];
  __shared__ float Dinv[kQR];

  // ---- stage queries + tables in LDS
  for (int idx = tid; idx < kQR*96; idx += 256) {
    int q = idx / 96, c = idx - q*96;
    int g = q / 7, jq = q - g*7;
    qs[q][c] = Q[((size_t)((bh*4 + g)*kSS + qi*14 + jhalf*7 + jq))*96 + c];
  }
  for (int idx = tid; idx < 864; idx += 256) frow[idx>>5][idx&31] = frow_g[idx];
  for (int idx = tid; idx < 864; idx += 256) fcol[idx>>5][idx&31] = fcol_g[idx];
  if (tid < 128) gembs[tid>>5][tid&31] = gemb_g[tid];
  __syncthreads();

  // ---- per-query bias dot tables: Ar (row), Ac (col), Ag (group)
  for (int t = tid; t < kQR*58; t += 256) {
    int q = t / 58, s = t - q*58;
    float acc = 0.f;
    if (s < 27) {
#pragma unroll
      for (int c = 0; c < 32; ++c) acc += qs[q][c] * frow[s][c];
      Arr[q][s] = acc;
    } else if (s < 54) {
      int n = s - 27;
#pragma unroll
      for (int c = 0; c < 32; ++c) acc += qs[q][32+c] * fcol[n][c];
      Acl[q][n] = acc;
    } else {
      int p = s - 54;
#pragma unroll
      for (int c = 0; c < 32; ++c) acc += qs[q][64+c] * gembs[p][c];
      Agg[q][p] = acc;
    }
  }
  __syncthreads();

  // ---- content logits: thread owns key kl=tid (<196), all 4 m groups
  if (tid < 196) {
#pragma unroll
    for (int m = 0; m < 4; ++m) {
      const float* kp = K + ((size_t)(bh*kKey + m*196 + tid))*96;
      float acc[kQR];
#pragma unroll
      for (int q = 0; q < kQR; ++q) acc[q] = 0.f;
      for (int cc = 0; cc < 96; cc += 4) {
        float4 kc = *(const float4*)(kp + cc);
#pragma unroll
        for (int q = 0; q < kQR; ++q) {
          float4 qv = *(const float4*)(&qs[q][cc]);
          acc[q] += kc.x*qv.x + kc.y*qv.y + kc.z*qv.z + kc.w*qv.w;
        }
      }
#pragma unroll
      for (int q = 0; q < kQR; ++q) contl[q][m*196 + tid] = __float2bfloat16(acc[q]);
    }
  }
  __syncthreads();

  const int kk = (tid < 196) ? (tid / 14) : 0;
  const int ll = (tid < 196) ? (tid % 14) : 0;
  const int da = kk - qi;

  for (int v = 0; v < 4; ++v) {
    // ---- pass A: max
    for (int q = 0; q < kQR; ++q) {
      float mq = -1e30f;
      if (tid < 196) {
        int gq = q / 7, jq = q - gq*7;
        int jj = jhalf*7 + jq;
        int db = ll - jj;
        int ai, ci;
        if (v == 0)      { ai =  da; ci =  db; }
        else if (v == 1) { ai = -db; ci =  da; }
        else if (v == 2) { ai = -da; ci = -db; }
        else             { ai =  db; ci = -da; }
        float arv = Arr[q][13+ai] + Acl[q][13+ci];
#pragma unroll
        for (int m = 0; m < 4; ++m) {
          float s = __bfloat162float(contl[q][m*196+tid]) + arv + Agg[q][(m - gq + v + 8) & 3];
          mq = fmaxf(mq, s);
        }
      }
#pragma unroll
      for (int off = 1; off < 64; off <<= 1) mq = fmaxf(mq, __shfl_xor(mq, off, 64));
      if ((tid & 63) == 0) redw[q][tid >> 6] = mq;
    }
    __syncthreads();
    if (tid < kQR)
      Ms[tid] = fmaxf(fmaxf(redw[tid][0], redw[tid][1]),
                      fmaxf(redw[tid][2], redw[tid][3])) * kScl;
    __syncthreads();

    // ---- pass B: denominator
    for (int q = 0; q < kQR; ++q) {
      float sq = 0.f;
      if (tid < 196) {
        int gq = q / 7, jq = q - gq*7;
        int jj = jhalf*7 + jq;
        int db = ll - jj;
        int ai, ci;
        if (v == 0)      { ai =  da; ci =  db; }
        else if (v == 1) { ai = -db; ci =  da; }
        else if (v == 2) { ai = -da; ci = -db; }
        else             { ai =  db; ci = -da; }
        float arv = Arr[q][13+ai] + Acl[q][13+ci];
        float mref = Ms[q];
#pragma unroll
        for (int m = 0; m < 4; ++m) {
          float s = __bfloat162float(contl[q][m*196+tid]) + arv + Agg[q][(m - gq + v + 8) & 3];
          sq += __expf(s*kScl - mref);
        }
      }
#pragma unroll
      for (int off = 1; off < 64; off <<= 1) sq += __shfl_xor(sq, off, 64);
      if ((tid & 63) == 0) redw[q][tid >> 6] = sq;
    }
    __syncthreads();
    if (tid < kQR)
      Dinv[tid] = 1.0f / (redw[tid][0] + redw[tid][1] + redw[tid][2] + redw[tid][3]);
    __syncthreads();

    // ---- pass C: normalized probs, summed over g, streamed to Psum
    if (tid < 196) {
      for (int jq = 0; jq < 7; ++jq) {
        int jj = jhalf*7 + jq;
        int db = ll - jj;
        int ai, ci;
        if (v == 0)      { ai =  da; ci =  db; }
        else if (v == 1) { ai = -db; ci =  da; }
        else if (v == 2) { ai = -da; ci = -db; }
        else             { ai =  db; ci = -da; }
        float am[4] = {0.f, 0.f, 0.f, 0.f};
#pragma unroll
        for (int gq = 0; gq < 4; ++gq) {
          int q = gq*7 + jq;
          float arv = Arr[q][13+ai] + Acl[q][13+ci];
          float mref = Ms[q], dv = Dinv[q];
#pragma unroll
          for (int m = 0; m < 4; ++m) {
            float s = __bfloat162float(contl[q][m*196+tid]) + arv + Agg[q][(m - gq + v + 8) & 3];
            am[m] += __expf(s*kScl - mref) * dv;
          }
        }
        float* pp = Psum + ((size_t)((bh*4 + v)*kSS + qi*14 + jj))*kKey + tid;
#pragma unroll
        for (int m = 0; m < 4; ++m) pp[m*196] = am[m];
      }
    }
    __syncthreads();
  }
}

// ============================================================
// Kernel 4: PV GEMM. Per (b,h,v, ij-tile of 49): [49 x 784] @ [784 x 96].
// 256 blocks -> exactly 1 per CU. Writes vo[b][v][ij][c*8+h].
// ============================================================
__global__ __launch_bounds__(256)
void k_pv(const float* __restrict__ Psum, const float* __restrict__ V,
          float* __restrict__ vo) {
  const int tid = threadIdx.x;
  const int bid = blockIdx.x;
  const int itile = bid & 3;
  const int v = (bid >> 2) & 3;
  const int h = (bid >> 4) & 7;
  const int b = bid >> 7;
  const int bh = b*8 + h;

  __shared__ float Ps[49][196];
  __shared__ float Vs[196][96];
  const int rg = tid >> 5;          // 0..7 (rg<7 active: 7 rows each)
  const int c3 = (tid & 31) * 3;    // 0..93
  float acc[7][3];
#pragma unroll
  for (int r = 0; r < 7; ++r) { acc[r][0] = 0.f; acc[r][1] = 0.f; acc[r][2] = 0.f; }

  const float* prow = Psum + ((size_t)((bh*4 + v)*kSS + itile*49))*kKey;
  const float* vrow = V + (size_t)bh*kKey*96;

  for (int mc = 0; mc < 4; ++mc) {
    for (int idx = tid; idx < 49*196; idx += 256) {
      int r = idx / 196, k = idx - r*196;
      Ps[r][k] = prow[(size_t)r*kKey + mc*196 + k];
    }
    for (int idx = tid; idx < 196*96; idx += 256)
      (&Vs[0][0])[idx] = vrow[(size_t)mc*196*96 + idx];
    __syncthreads();
    if (rg < 7) {
      for (int k = 0; k < 196; ++k) {
        float v0 = Vs[k][c3], v1 = Vs[k][c3+1], v2 = Vs[k][c3+2];
#pragma unroll
        for (int rr = 0; rr < 7; ++rr) {
          float p = Ps[rg*7+rr][k];
          acc[rr][0] += p*v0; acc[rr][1] += p*v1; acc[rr][2] += p*v2;
        }
      }
    }
    __syncthreads();
  }
  if (rg < 7) {
#pragma unroll
    for (int rr = 0; rr < 7; ++rr) {
      int ij = itile*49 + rg*7 + rr;
      float* op = vo + ((size_t)((b*4 + v)*kSS + ij))*768 + h;
#pragma unroll
      for (int cc = 0; cc < 3; ++cc) op[(c3+cc)*8] = acc[rr][cc];
    }
  }
}

// ============================================================
// Kernel 5: output projection. out[b][d][v][ij] = Wo[d] . vo[b,v,ij,:] + bo[d]
// ============================================================
__global__ __launch_bounds__(256)
void k_outproj(const float* __restrict__ vo, const float* __restrict__ Wo,
               const float* __restrict__ bo, float* __restrict__ out) {
  const int tid = threadIdx.x;
  const int bid = blockIdx.x;
  const int i = bid % 14;
  const int v = (bid / 14) & 3;
  const int b = bid / 56;

  __shared__ float vos[14][772];   // pad 768->772 to break bank conflicts
  const float* src = vo + ((size_t)((b*4 + v)*kSS + i*14))*768;
  for (int idx = tid; idx < 14*768; idx += 256)
    vos[idx / 768][idx % 768] = src[idx];
  __syncthreads();

  for (int oi = tid; oi < 96*14; oi += 256) {
    int d = oi / 14, j = oi % 14;
    const float* wrow = Wo + (size_t)d*768;
    float a = bo[d];
    for (int c = 0; c < 768; c += 4) {
      float4 w = *(const float4*)(wrow + c);
      float4 vv = *(const float4*)(&vos[j][c]);
      a += w.x*vv.x + w.y*vv.y + w.z*vv.z + w.w*vv.w;
    }
    out[((size_t)(b*96 + d)*4 + v)*kSS + i*14 + j] = a;
  }
}

// ============================================================
extern "C" void kernel_launch(void* const* d_in, const int* in_sizes, int n_in,
                              void* d_out, int out_size, void* d_ws, size_t ws_size,
                              hipStream_t stream) {
  const float* x    = (const float*)d_in[0];
  const float* Wq   = (const float*)d_in[1];
  const float* bq   = (const float*)d_in[2];
  const float* Wk   = (const float*)d_in[3];
  const float* bk   = (const float*)d_in[4];
  const float* Wv   = (const float*)d_in[5];
  const float* bv   = (const float*)d_in[6];
  const float* Wo   = (const float*)d_in[7];
  const float* bo   = (const float*)d_in[8];
  const float* rw1  = (const float*)d_in[9];
  const float* rb1  = (const float*)d_in[10];
  const float* rgam = (const float*)d_in[11];
  const float* rbet = (const float*)d_in[12];
  const float* rw2  = (const float*)d_in[13];
  const float* rb2  = (const float*)d_in[14];
  const float* cw1  = (const float*)d_in[15];
  const float* cb1  = (const float*)d_in[16];
  const float* cgam = (const float*)d_in[17];
  const float* cbet = (const float*)d_in[18];
  const float* cw2  = (const float*)d_in[19];
  const float* cb2  = (const float*)d_in[20];
  const float* gemb = (const float*)d_in[21];
  // d_in[22..24] = row_rel, col_rel, g_idx: reconstructed analytically.

  float* ws = (float*)d_ws;
  float* Q    = ws + OFF_Q;
  float* K    = ws + OFF_K;
  float* V    = ws + OFF_V;
  float* Frow = ws + OFF_FR;
  float* Fcol = ws + OFF_FC;
  float* Ps   = ws + OFF_PS;
  float* VO   = ws + OFF_VO;
  float* out  = (float*)d_out;

  k_tables<<<1, 64, 0, stream>>>(rw1, rb1, rgam, rbet, rw2, rb2,
                                 cw1, cb1, cgam, cbet, cw2, cb2, Frow, Fcol);
  k_qkv<<<dim3(112, 3), 256, 0, stream>>>(x, Wq, bq, Wk, bk, Wv, bv, Q, K, V);
  k_attn<<<448, 256, 0, stream>>>(Q, K, Frow, Fcol, gemb, Ps);
  k_pv<<<256, 256, 0, stream>>>(Ps, V, VO);
  k_outproj<<<112, 256, 0, stream>>>(VO, Wo, bo, out);
}

// Round 3
// 385.396 us; speedup vs baseline: 1.2971x; 1.2971x over previous
//
#include <hip/hip_runtime.h>
#include <hip/hip_bf16.h>

// Problem constants
constexpr int kB   = 2;
constexpr int kH   = 8;
constexpr int kG   = 4;
constexpr int kS   = 14;
constexpr int kSS  = 196;   // S*S
constexpr int kKey = 784;   // G*S*S keys per (b,h)
constexpr int kMid = 96;
constexpr int kQR  = 28;    // 4 g * 7 j query rows per attention block
constexpr float kScl = 0.10206207261596577f; // 1/sqrt(96)
constexpr float kK2  = 0.14724663682f;       // kScl / ln(2)  (exp2 domain)
constexpr float kCc  = 11.5415603272f;       // 8 nats / ln(2): constant softmax shift (exact)

// ---------------- workspace layout (float elements) ----------------
constexpr size_t SZ_QKV = (size_t)kB*kH*kG*kSS*kMid;   // 1,204,224
constexpr size_t OFF_Q  = 0;
constexpr size_t OFF_K  = OFF_Q + SZ_QKV;              // K stored CHANNEL-MAJOR: [bh][c][key784]
constexpr size_t OFF_V  = OFF_K + SZ_QKV;
constexpr size_t OFF_FR = OFF_V + SZ_QKV;              // 27*32 row table
constexpr size_t OFF_FC = OFF_FR + 27*32;              // 27*32 col table
constexpr size_t OFF_PS = OFF_FC + 27*32;              // Psum
constexpr size_t SZ_PS  = (size_t)kB*kH*kG*kSS*kKey;   // 9,834,496
constexpr size_t OFF_VO = OFF_PS + SZ_PS;              // vo: 1,204,224

// ============================================================
// Kernel 1: embed tables. row_rel/col_rel only take values n/13, n in [-13,13],
// so the whole (G,S,S,S,S,32) embed tensors reduce to two 27x32 tables.
// ============================================================
__global__ void k_tables(const float* __restrict__ rw1, const float* __restrict__ rb1,
                         const float* __restrict__ rgam, const float* __restrict__ rbet,
                         const float* __restrict__ rw2, const float* __restrict__ rb2,
                         const float* __restrict__ cw1, const float* __restrict__ cb1,
                         const float* __restrict__ cgam, const float* __restrict__ cbet,
                         const float* __restrict__ cw2, const float* __restrict__ cb2,
                         float* __restrict__ frow, float* __restrict__ fcol) {
  int t = threadIdx.x;
  if (t >= 54) return;
  int which = t / 27;
  int n = t % 27;
  float tv = (float)(n - 13) / 13.0f;
  const float* w1  = which ? cw1  : rw1;
  const float* b1  = which ? cb1  : rb1;
  const float* gam = which ? cgam : rgam;
  const float* bet = which ? cbet : rbet;
  const float* w2  = which ? cw2  : rw2;
  const float* b2  = which ? cb2  : rb2;
  float h[16];
  float mu = 0.f;
#pragma unroll
  for (int d = 0; d < 16; ++d) { h[d] = tv * w1[d] + b1[d]; mu += h[d]; }
  mu *= (1.0f/16.0f);
  float var = 0.f;
#pragma unroll
  for (int d = 0; d < 16; ++d) { float z = h[d] - mu; var += z*z; }
  var *= (1.0f/16.0f);
  float rstd = rsqrtf(var + 1e-5f);
#pragma unroll
  for (int d = 0; d < 16; ++d) {
    float z = (h[d] - mu) * rstd * gam[d] + bet[d];
    h[d] = z / (1.0f + expf(-z));   // silu
  }
  float* outp = (which ? fcol : frow) + n*32;
  for (int c = 0; c < 32; ++c) {
    float o = b2[c];
#pragma unroll
    for (int d = 0; d < 16; ++d) o += h[d] * w2[d*32 + c];
    outp[c] = o;
  }
}

// ============================================================
// Kernel 2: QKV projection (R1-proven body; only the K store changed).
// Q,V layout: [b][h][g][ij][c] (c contiguous).  K layout: CHANNEL-MAJOR
// [b][h][c][g*196+ij] so the attention GEMM's K loads are coalesced.
// d = c*8 + h per the reference reshape(MID, HEADS).
// ============================================================
__global__ __launch_bounds__(256)
void k_qkv(const float* __restrict__ x,
           const float* __restrict__ Wq, const float* __restrict__ bq,
           const float* __restrict__ Wk, const float* __restrict__ bk,
           const float* __restrict__ Wv, const float* __restrict__ bv,
           float* __restrict__ Q, float* __restrict__ K, float* __restrict__ V) {
  const int bid = blockIdx.x;
  const int ten = blockIdx.y;
  const int i = bid % 14;
  const int g = (bid / 14) % 4;
  const int b = bid / 56;
  const float* W    = (ten == 0) ? Wq : (ten == 1) ? Wk : Wv;
  const float* bias = (ten == 0) ? bq : (ten == 1) ? bk : bv;
  float* O          = (ten == 0) ? Q  : (ten == 1) ? K  : V;

  __shared__ float xs[96][14];
  for (int idx = threadIdx.x; idx < 96*14; idx += 256) {
    int cin = idx / 14, j = idx % 14;
    xs[cin][j] = x[((size_t)(b*96 + cin)*4 + g)*196 + i*14 + j];
  }
  __syncthreads();

  for (int d = threadIdx.x; d < 768; d += 256) {
    int c = d >> 3, h = d & 7;
    float bvv = bias[d];
    float acc[14];
#pragma unroll
    for (int j = 0; j < 14; ++j) acc[j] = bvv;
    const float* wrow = W + (size_t)d * 96;
    for (int cc = 0; cc < 96; cc += 4) {
      float4 w = *(const float4*)(wrow + cc);
#pragma unroll
      for (int j = 0; j < 14; ++j)
        acc[j] += w.x*xs[cc][j] + w.y*xs[cc+1][j] + w.z*xs[cc+2][j] + w.w*xs[cc+3][j];
    }
    if (ten == 1) {
      // channel-major K: [bh*96 + c][g*196 + i*14 + j]
      float* op = K + ((size_t)((b*8 + h)*96 + c))*784 + g*196 + i*14;
#pragma unroll
      for (int j = 0; j < 14; ++j) op[j] = acc[j];
    } else {
      float* op = O + ((size_t)((b*8 + h)*4 + g)*196 + i*14)*96 + c;
#pragma unroll
      for (int j = 0; j < 14; ++j) op[(size_t)j*96] = acc[j];
    }
  }
}

// ============================================================
// Kernel 3: fused content + bias + softmax (R1 skeleton, new math).
// Block = (b,h,i,jhalf): 28 query rows (4 g x 7 j) vs 784 keys.
//
// exp2 domain with constant shift Cc (exact for softmax):
//   e(q,m,kl;v) = E(q,m,kl) * arvE(q;v,kl) * AgErot(q,m;v)
// E = exp2(content*kK2 - Cc) is v-INDEPENDENT: computed once, bf16 in LDS.
// No max pass. One shuffle-reduction (denominator) per v. Pass C has zero
// transcendentals.
// ============================================================
__global__ __launch_bounds__(256, 2)
void k_attn(const float* __restrict__ Q, const float* __restrict__ Kt,
            const float* __restrict__ frow_g, const float* __restrict__ fcol_g,
            const float* __restrict__ gemb_g, float* __restrict__ Psum) {
  const int tid = threadIdx.x;
  const int bid = blockIdx.x;
  const int jhalf = bid & 1;
  const int t2 = bid >> 1;
  const int qi = t2 % 14;
  const int hh = (t2 / 14) % 8;
  const int bb = t2 / 112;
  const int bh = bb*8 + hh;

  __shared__ alignas(16) float qs[kQR][96];
  __shared__ alignas(16) float frowS[27*32];
  __shared__ alignas(16) float fcolS[27*32];
  __shared__ alignas(16) float gembS[128];
  __shared__ float Arr2[kQR][27];             // row bias dot, pre-scaled by kK2
  __shared__ float Acl2[kQR][27];             // col bias dot, pre-scaled by kK2
  __shared__ float AgE[kQR][4];               // exp2(group bias * kK2)
  __shared__ float AgErot[kQR][4];            // per-v rotated AgE
  __shared__ float redw[kQR][4];
  __shared__ float DinvS[kQR];
  __shared__ __hip_bfloat16 contl[kQR][kKey]; // E values: [q][m*196 + kl]

  // ---- stage queries + tables (tables pre-scaled into exp2 domain)
  for (int idx = tid; idx < kQR*96; idx += 256) {
    int q = idx / 96, c = idx - q*96;
    int g = q / 7, jq = q - g*7;
    qs[q][c] = Q[((size_t)((bh*4 + g)*kSS + qi*14 + jhalf*7 + jq))*96 + c];
  }
  for (int idx = tid; idx < 864; idx += 256) frowS[idx] = frow_g[idx] * kK2;
  for (int idx = tid; idx < 864; idx += 256) fcolS[idx] = fcol_g[idx] * kK2;
  if (tid < 128) gembS[tid] = gemb_g[tid] * kK2;
  __syncthreads();

  // ---- per-query bias tables (exp2 domain)
  for (int t = tid; t < kQR*58; t += 256) {
    int q = t / 58, s = t - q*58;
    float acc = 0.f;
    if (s < 27) {
#pragma unroll
      for (int c = 0; c < 32; ++c) acc += qs[q][c] * frowS[s*32 + c];
      Arr2[q][s] = acc;
    } else if (s < 54) {
      int n = s - 27;
#pragma unroll
      for (int c = 0; c < 32; ++c) acc += qs[q][32+c] * fcolS[n*32 + c];
      Acl2[q][n] = acc;
    } else {
      int p = s - 54;
#pragma unroll
      for (int c = 0; c < 32; ++c) acc += qs[q][64+c] * gembS[p*32 + c];
      AgE[q][p] = exp2f(acc);
    }
  }
  __syncthreads();

  // ---- content GEMM: thread owns key-col kl=tid (<196), all 4 m in registers.
  // K channel-major -> coalesced global loads; 16 FMA per ds_read_b128 of q.
  if (tid < 196) {
    const float* kb = Kt + (size_t)bh*96*784 + tid;
    for (int h2 = 0; h2 < 2; ++h2) {
      float acc[14][4];
#pragma unroll
      for (int q = 0; q < 14; ++q)
#pragma unroll
        for (int m = 0; m < 4; ++m) acc[q][m] = 0.f;
      for (int cc = 0; cc < 96; cc += 4) {
        float kf[4][4];
#pragma unroll
        for (int c = 0; c < 4; ++c)
#pragma unroll
          for (int m = 0; m < 4; ++m)
            kf[c][m] = kb[(size_t)(cc + c)*784 + m*196];
#pragma unroll
        for (int q = 0; q < 14; ++q) {
          float4 qv = *(const float4*)(&qs[h2*14 + q][cc]);
#pragma unroll
          for (int m = 0; m < 4; ++m)
            acc[q][m] += qv.x*kf[0][m] + qv.y*kf[1][m] + qv.z*kf[2][m] + qv.w*kf[3][m];
        }
      }
      // E = exp2(content*kK2 - Cc), scalar bf16 stores (R1-proven layout)
#pragma unroll
      for (int q = 0; q < 14; ++q)
#pragma unroll
        for (int m = 0; m < 4; ++m)
          contl[h2*14 + q][m*196 + tid] = __float2bfloat16(exp2f(acc[q][m]*kK2 - kCc));
    }
  }
  __syncthreads();

  const int kk = (tid < 196) ? (tid / 14) : 0;
  const int ll = (tid < 196) ? (tid % 14) : 0;
  const int da = kk - qi;

  for (int v = 0; v < 4; ++v) {
    // rotation coefficients: (ai,ci) = v-rotation of (da,db)
    int s1a, s1b, s2a, s2b;
    if (v == 0)      { s1a = 1;  s1b = 0;  s2a = 0;  s2b = 1;  }
    else if (v == 1) { s1a = 0;  s1b = -1; s2a = 1;  s2b = 0;  }
    else if (v == 2) { s1a = -1; s1b = 0;  s2a = 0;  s2b = -1; }
    else             { s1a = 0;  s1b = 1;  s2a = -1; s2b = 0;  }

    if (tid < 112) {
      int q = tid >> 2, m = tid & 3, gq = q / 7;
      AgErot[q][m] = AgE[q][(m - gq + v + 8) & 3];
    }
    __syncthreads();

    // ---- pass B: denominators. Per-thread partial per q, shuffle-reduce.
    float arvE[kQR];
    float prt[kQR];
    if (tid < 196) {
#pragma unroll
      for (int gq = 0; gq < 4; ++gq) {
#pragma unroll
        for (int jq = 0; jq < 7; ++jq) {
          const int q = gq*7 + jq;
          const int db = ll - (jhalf*7 + jq);
          const int ai = s1a*da + s1b*db, ci = s2a*da + s2b*db;
          arvE[q] = exp2f(Arr2[q][13 + ai] + Acl2[q][13 + ci]);
          float e0 = __bfloat162float(contl[q][0*196 + tid]);
          float e1 = __bfloat162float(contl[q][1*196 + tid]);
          float e2 = __bfloat162float(contl[q][2*196 + tid]);
          float e3 = __bfloat162float(contl[q][3*196 + tid]);
          prt[q] = (e0*AgErot[q][0] + e1*AgErot[q][1] +
                    e2*AgErot[q][2] + e3*AgErot[q][3]) * arvE[q];
        }
      }
    } else {
#pragma unroll
      for (int q = 0; q < kQR; ++q) { prt[q] = 0.f; arvE[q] = 0.f; }
    }
#pragma unroll
    for (int q = 0; q < kQR; ++q) {
      float s = prt[q];
#pragma unroll
      for (int off = 1; off < 64; off <<= 1) s += __shfl_xor(s, off, 64);
      if ((tid & 63) == 0) redw[q][tid >> 6] = s;
    }
    __syncthreads();
    if (tid < kQR)
      DinvS[tid] = 1.0f / (redw[tid][0] + redw[tid][1] + redw[tid][2] + redw[tid][3]);
    __syncthreads();

    // ---- pass C: normalized probs (no transcendentals), summed over g
    if (tid < 196) {
      float* pbase = Psum + ((size_t)((bh*4 + v)*kSS + qi*14 + jhalf*7))*kKey + tid;
#pragma unroll
      for (int jq = 0; jq < 7; ++jq) {
        float am[4] = {0.f, 0.f, 0.f, 0.f};
#pragma unroll
        for (int gq = 0; gq < 4; ++gq) {
          const int q = gq*7 + jq;
          const float fq = arvE[q] * DinvS[q];
          float e0 = __bfloat162float(contl[q][0*196 + tid]);
          float e1 = __bfloat162float(contl[q][1*196 + tid]);
          float e2 = __bfloat162float(contl[q][2*196 + tid]);
          float e3 = __bfloat162float(contl[q][3*196 + tid]);
          am[0] += e0 * (AgErot[q][0] * fq);
          am[1] += e1 * (AgErot[q][1] * fq);
          am[2] += e2 * (AgErot[q][2] * fq);
          am[3] += e3 * (AgErot[q][3] * fq);
        }
        float* pp = pbase + (size_t)jq*kKey;
#pragma unroll
        for (int m = 0; m < 4; ++m) pp[m*196] = am[m];
      }
    }
    __syncthreads();   // protects AgErot for next v
  }
}

// ============================================================
// Kernel 4: PV GEMM. Per (b,h,v, ij-tile of 49): [49 x 784] @ [784 x 96].
// 256 blocks -> exactly 1 block/CU. Writes vo[b][v][ij][c*8+h].
// ============================================================
__global__ __launch_bounds__(256)
void k_pv(const float* __restrict__ Psum, const float* __restrict__ V,
          float* __restrict__ vo) {
  const int tid = threadIdx.x;
  const int bid = blockIdx.x;
  const int itile = bid & 3;
  const int v = (bid >> 2) & 3;
  const int h = (bid >> 4) & 7;
  const int b = bid >> 7;
  const int bh = b*8 + h;

  __shared__ float Ps[49][196];
  __shared__ float Vs[196][96];
  const int rg = tid >> 5;          // 0..7 (rg<7 active: 7 rows each)
  const int c3 = (tid & 31) * 3;    // 0..93
  float acc[7][3];
#pragma unroll
  for (int r = 0; r < 7; ++r) { acc[r][0] = 0.f; acc[r][1] = 0.f; acc[r][2] = 0.f; }

  const float* prow = Psum + ((size_t)((bh*4 + v)*kSS + itile*49))*kKey;
  const float* vrow = V + (size_t)bh*kKey*96;

  for (int mc = 0; mc < 4; ++mc) {
    for (int idx = tid; idx < 49*196; idx += 256) {
      int r = idx / 196, k = idx - r*196;
      Ps[r][k] = prow[(size_t)r*kKey + mc*196 + k];
    }
    for (int idx = tid; idx < 196*96; idx += 256)
      (&Vs[0][0])[idx] = vrow[(size_t)mc*196*96 + idx];
    __syncthreads();
    if (rg < 7) {
      for (int k = 0; k < 196; ++k) {
        float v0 = Vs[k][c3], v1 = Vs[k][c3+1], v2 = Vs[k][c3+2];
#pragma unroll
        for (int rr = 0; rr < 7; ++rr) {
          float p = Ps[rg*7+rr][k];
          acc[rr][0] += p*v0; acc[rr][1] += p*v1; acc[rr][2] += p*v2;
        }
      }
    }
    __syncthreads();
  }
  if (rg < 7) {
#pragma unroll
    for (int rr = 0; rr < 7; ++rr) {
      int ij = itile*49 + rg*7 + rr;
      float* op = vo + ((size_t)((b*4 + v)*kSS + ij))*768 + h;
#pragma unroll
      for (int cc = 0; cc < 3; ++cc) op[(c3+cc)*8] = acc[rr][cc];
    }
  }
}

// ============================================================
// Kernel 5: output projection. out[b][d][v][ij] = Wo[d] . vo[b,v,ij,:] + bo[d]
// ============================================================
__global__ __launch_bounds__(256)
void k_outproj(const float* __restrict__ vo, const float* __restrict__ Wo,
               const float* __restrict__ bo, float* __restrict__ out) {
  const int tid = threadIdx.x;
  const int bid = blockIdx.x;
  const int i = bid % 14;
  const int v = (bid / 14) & 3;
  const int b = bid / 56;

  __shared__ alignas(16) float vos[14][772];   // pad 768->772: bank-conflict break
  const float* src = vo + ((size_t)((b*4 + v)*kSS + i*14))*768;
  for (int idx = tid; idx < 14*768; idx += 256)
    vos[idx / 768][idx % 768] = src[idx];
  __syncthreads();

  for (int oi = tid; oi < 96*14; oi += 256) {
    int d = oi / 14, j = oi % 14;
    const float* wrow = Wo + (size_t)d*768;
    float a = bo[d];
    for (int c = 0; c < 768; c += 4) {
      float4 w = *(const float4*)(wrow + c);
      float4 vv = *(const float4*)(&vos[j][c]);
      a += w.x*vv.x + w.y*vv.y + w.z*vv.z + w.w*vv.w;
    }
    out[((size_t)(b*96 + d)*4 + v)*kSS + i*14 + j] = a;
  }
}

// ============================================================
extern "C" void kernel_launch(void* const* d_in, const int* in_sizes, int n_in,
                              void* d_out, int out_size, void* d_ws, size_t ws_size,
                              hipStream_t stream) {
  const float* x    = (const float*)d_in[0];
  const float* Wq   = (const float*)d_in[1];
  const float* bq   = (const float*)d_in[2];
  const float* Wk   = (const float*)d_in[3];
  const float* bk   = (const float*)d_in[4];
  const float* Wv   = (const float*)d_in[5];
  const float* bv   = (const float*)d_in[6];
  const float* Wo   = (const float*)d_in[7];
  const float* bo   = (const float*)d_in[8];
  const float* rw1  = (const float*)d_in[9];
  const float* rb1  = (const float*)d_in[10];
  const float* rgam = (const float*)d_in[11];
  const float* rbet = (const float*)d_in[12];
  const float* rw2  = (const float*)d_in[13];
  const float* rb2  = (const float*)d_in[14];
  const float* cw1  = (const float*)d_in[15];
  const float* cb1  = (const float*)d_in[16];
  const float* cgam = (const float*)d_in[17];
  const float* cbet = (const float*)d_in[18];
  const float* cw2  = (const float*)d_in[19];
  const float* cb2  = (const float*)d_in[20];
  const float* gemb = (const float*)d_in[21];
  // d_in[22..24] = row_rel, col_rel, g_idx: reconstructed analytically.

  float* ws = (float*)d_ws;
  float* Q    = ws + OFF_Q;
  float* K    = ws + OFF_K;
  float* V    = ws + OFF_V;
  float* Frow = ws + OFF_FR;
  float* Fcol = ws + OFF_FC;
  float* Ps   = ws + OFF_PS;
  float* VO   = ws + OFF_VO;
  float* out  = (float*)d_out;

  k_tables<<<1, 64, 0, stream>>>(rw1, rb1, rgam, rbet, rw2, rb2,
                                 cw1, cb1, cgam, cbet, cw2, cb2, Frow, Fcol);
  k_qkv<<<dim3(112, 3), 256, 0, stream>>>(x, Wq, bq, Wk, bk, Wv, bv, Q, K, V);
  k_attn<<<448, 256, 0, stream>>>(Q, K, Frow, Fcol, gemb, Ps);
  k_pv<<<256, 256, 0, stream>>>(Ps, V, VO);
  k_outproj<<<112, 256, 0, stream>>>(VO, Wo, bo, out);
}